// Round 18
// baseline (22.800 us; speedup 1.0000x reference)
//
#include <hip/hip_runtime.h>

// ---------------------------------------------------------------------------
// VQC_Net fully fused, SINGLE kernel: probs[b,c] = ((RY2 * D * RY1) amp)^2[c]
// R18 = R17 with ONE change: TILES=2 -> 4096 blocks = 2 generations/CU.
// Gen 2's read ramp overlaps gen 1's store drain (R10 tested this bundled
// with NT loads, which poisoned the result; this is the clean test).
// Math (R17): product-state fusion of RY1 (4 monomial 2-vector rotations
// before the Kronecker amp build), D sign flips {3,6,9,12}, RY2 as monomial
// butterflies with SGPR-uniform branches, total scale folded into v3.
// Skeleton lessons kept: wave-private LDS staging, zero barriers (R8);
// NT stores, regular loads (R10/R11); front-loaded x reads (R12); LDS
// transpose essential (R7); no vmcnt-draining waits (R6); fused single
// kernel + in-kernel fast trig (R13); (256,8) (R15); SGPR-uniform monomial
// control (R16); RY1 product fusion (R17).
// ---------------------------------------------------------------------------

typedef float f32x4 __attribute__((ext_vector_type(4)));

#if defined(__has_builtin)
#if __has_builtin(__builtin_amdgcn_sqrtf)
#define FSQRT(x) __builtin_amdgcn_sqrtf(x)
#endif
#endif
#ifndef FSQRT
#define FSQRT(x) sqrtf(x)
#endif

__device__ __forceinline__ float rfl(float v) {
    return __int_as_float(__builtin_amdgcn_readfirstlane(__float_as_int(v)));
}
__device__ __forceinline__ int rfl(int v) {
    return __builtin_amdgcn_readfirstlane(v);
}

#define TILES 2   // 2 x 256 samples per block; 2M / 512 = 4096 blocks = 2 gens

__global__ __launch_bounds__(256, 8) void vqc_main(const f32x4* __restrict__ x,
                                                   const float* __restrict__ theta,
                                                   float* __restrict__ out,
                                                   int nsamp) {
    // wave-private double-buffered staging: [wave][buf][640 floats]
    __shared__ float sBuf[4][2][640];   // 20 KB

    int tid = threadIdx.x;
    int wid = tid >> 6;
    int lane = tid & 63;

    long long base = (long long)blockIdx.x * (TILES * 256);

    // FRONT-LOAD both tiles of x (issued back-to-back; 2 outstanding vmem).
    f32x4 xv[TILES];
#pragma unroll
    for (int t = 0; t < TILES; ++t) {
        long long bt = base + (long long)t * 256 + tid;
        if (bt < nsamp) xv[t] = x[bt];
    }

    // Uniform monomial coefficients (SGPR), stages 0..3 = RY1, 4..7 = RY2.
    float w[8];
    int   ct[8];          // 1 = cot form (|s| > |c|), 0 = tan form
    float scale = 1.0f;
#pragma unroll
    for (int q = 0; q < 8; ++q) {
        float h = 0.5f * theta[q];
        float c = __cosf(h), s = __sinf(h);
        int cot = rfl(fabsf(s) > fabsf(c) ? 1 : 0);
        ct[q] = cot;
        w[q]  = rfl(cot ? (c / s) : (s / c));
        scale *= cot ? s : c;
    }
    scale = rfl(scale);

#pragma unroll
    for (int t = 0; t < TILES; ++t) {
        long long tileStart = base + (long long)t * 256;
        long long b = tileStart + tid;

        int p = t & 1;
        float* myBuf = sBuf[wid][p];

        if (b < nsamp) {
            // ---- per-qubit 2-vectors (amp bit q) ----
            float va[4], vb[4];
            if (b == 0) {
                // little-endian, raw probs, no sqrt: amp bit q <-> x qubit q
                va[0] = 1.0f - xv[t].x; vb[0] = xv[t].x;
                va[1] = 1.0f - xv[t].y; vb[1] = xv[t].y;
                va[2] = 1.0f - xv[t].z; vb[2] = xv[t].z;
                va[3] = 1.0f - xv[t].w; vb[3] = xv[t].w;
            } else {
                // big-endian, squared probs, sqrt: amp bit q <-> x qubit 3-q
                float p0 = xv[t].x * xv[t].x, p1 = xv[t].y * xv[t].y;
                float p2 = xv[t].z * xv[t].z, p3 = xv[t].w * xv[t].w;
                va[0] = FSQRT(1.0f - p3); vb[0] = FSQRT(p3);
                va[1] = FSQRT(1.0f - p2); vb[1] = FSQRT(p2);
                va[2] = FSQRT(1.0f - p1); vb[2] = FSQRT(p1);
                va[3] = FSQRT(1.0f - p0); vb[3] = FSQRT(p0);
            }

            // ---- RY1 fused: rotate each 2-vector (monomial, 2 FMA each) ----
#pragma unroll
            for (int q = 0; q < 4; ++q) {
                float A = va[q], B = vb[q];
                if (ct[q]) { va[q] = fmaf(w[q], A, -B); vb[q] = fmaf(w[q], B, A); }
                else       { va[q] = fmaf(-w[q], B, A); vb[q] = fmaf(w[q], A, B); }
            }

            // fold total uniform scale into qubit-3 vector
            va[3] *= scale; vb[3] *= scale;

            // ---- outer-product amp build ----
            float hi[4] = { va[3] * va[2], va[3] * vb[2],
                            vb[3] * va[2], vb[3] * vb[2] };
            float lo[4] = { va[1] * va[0], va[1] * vb[0],
                            vb[1] * va[0], vb[1] * vb[0] };
            float amp[16];
#pragma unroll
            for (int k = 0; k < 16; ++k)
                amp[k] = hi[k >> 2] * lo[k & 3];

            // D: sign flips at k = 3, 6, 9, 12
            amp[3]  = -amp[3];
            amp[6]  = -amp[6];
            amp[9]  = -amp[9];
            amp[12] = -amp[12];

            // ---- RY2 monomial butterflies (bits 0..2) ----
#define BFLY(Q, W, CT)                                                   \
            if (CT) {                                                    \
                _Pragma("unroll")                                        \
                for (int i0 = 0; i0 < 16; ++i0)                          \
                    if (!(i0 & (1 << (Q)))) {                            \
                        int i1 = i0 | (1 << (Q));                        \
                        float A = amp[i0], B = amp[i1];                  \
                        amp[i0] = fmaf((W), A, -B);                      \
                        amp[i1] = fmaf((W), B, A);                       \
                    }                                                    \
            } else {                                                     \
                _Pragma("unroll")                                        \
                for (int i0 = 0; i0 < 16; ++i0)                          \
                    if (!(i0 & (1 << (Q)))) {                            \
                        int i1 = i0 | (1 << (Q));                        \
                        float A = amp[i0], B = amp[i1];                  \
                        amp[i0] = fmaf(-(W), B, A);                      \
                        amp[i1] = fmaf((W), A, B);                       \
                    }                                                    \
            }

            BFLY(0, w[4], ct[4])
            BFLY(1, w[5], ct[5])
            BFLY(2, w[6], ct[6])
#undef BFLY

            // RY2 qubit-3 stage: only the 10 needed rows
            float r[10];
            if (ct[7]) {
#pragma unroll
                for (int i = 0; i < 8; ++i)
                    r[i] = fmaf(w[7], amp[i], -amp[i + 8]);
                r[8] = fmaf(w[7], amp[8], amp[0]);
                r[9] = fmaf(w[7], amp[9], amp[1]);
            } else {
#pragma unroll
                for (int i = 0; i < 8; ++i)
                    r[i] = fmaf(-w[7], amp[i + 8], amp[i]);
                r[8] = fmaf(w[7], amp[0], amp[8]);
                r[9] = fmaf(w[7], amp[1], amp[9]);
            }

#pragma unroll
            for (int c = 0; c < 10; ++c)
                myBuf[lane * 10 + c] = r[c] * r[c];   // 4-way bank alias: ~free
        }

        // drain OWN ds ops - intra-wave only, no barrier (wave-private slice)
        asm volatile("s_waitcnt lgkmcnt(0)" ::: "memory");

        long long waveBase = tileStart + (long long)(wid << 6);
        long long wrem = (long long)nsamp - waveBase;
        if (wrem >= 64) {
            // wave's 64 samples = 2560B contiguous in out, line-aligned.
            // NONTEMPORAL: out is write-once -> no-allocate, no L2/L3 churn.
            f32x4* ov = (f32x4*)(out + waveBase * 10);
            const f32x4* sv = (const f32x4*)myBuf;
#pragma unroll
            for (int i = lane; i < 160; i += 64)
                __builtin_nontemporal_store(sv[i], &ov[i]);
        } else if (wrem > 0) {
            int n = (int)wrem * 10;
            for (int i = lane; i < n; i += 64)
                out[waveBase * 10 + i] = myBuf[i];
        }
        // WAR on buffer p (reused at t+2): protected by the lgkmcnt(0) at
        // t+1, which drains this tile's flush ds_reads before t+2's writes.
    }
}

extern "C" void kernel_launch(void* const* d_in, const int* in_sizes, int n_in,
                              void* d_out, int out_size, void* d_ws, size_t ws_size,
                              hipStream_t stream) {
    const float* x = (const float*)d_in[0];      // [B,4] f32
    const float* theta = (const float*)d_in[1];  // [8]   f32
    float* out = (float*)d_out;                  // [B,10] f32

    int nsamp = in_sizes[0] / 4;
    int spb = TILES * 256;
    int blocks = (nsamp + spb - 1) / spb;
    vqc_main<<<blocks, 256, 0, stream>>>((const f32x4*)x, theta, out, nsamp);
}

// Round 19
// 22.160 us; speedup vs baseline: 1.0289x; 1.0289x over previous
//
#include <hip/hip_runtime.h>

// ---------------------------------------------------------------------------
// VQC_Net fully fused, SINGLE kernel: probs[b,c] = ((RY2 * D * RY1) amp)^2[c]
// FINAL (= R17, best measured: 22.24 us; R18's TILES=2 regressed to 22.8).
// Math: product-state fusion of RY1 (amp is a Kronecker product of four
// 2-vectors; RY1 factors through it -> 4 monomial 2-vector rotations, 8 FMA),
// D sign flips {3,6,9,12}, RY2 as monomial butterflies (2 FMA/pair) with
// SGPR-uniform (readfirstlane) branch selection, total scale folded into v3,
// final stage emits only the 10 needed rows.
// Ladder of measured lessons baked in:
//   R1  s_load/uniform-operand matvec beats LDS-read matvec (R4: DS-pipe)
//   R6  __syncthreads' vmcnt(0) drain convoys the store stream -> no barriers
//   R7  direct stride-40B stores = 10x line-request amplification (2.2 TB/s)
//       -> LDS transpose to contiguous dwordx4 flush is essential
//   R8  wave-private LDS slices -> lgkmcnt(0) only, zero block barriers
//   R10 NT loads kill x's inter-replay L3 residency (FETCH 16->32 MB)
//   R11 NT stores (write-once out): -1.4 us of L2/L3 dirty churn
//   R12 front-load all 4 tiles' reads -> pure store steady-state (-1.5 us)
//   R13 fuse build_T away (in-kernel fast trig): -3.8 us graph node
//   R14 data-dependent branches predicate BOTH paths; >64 VGPR at (256,8)
//       spills -> keep control SGPR-uniform, pressure low
//   R15 (256,8): the 8th wave/SIMD is worth ~1 us vs (256,4)
//   R16 monomial butterflies +SGPR branches: -1.3 us
//   R17 RY1 product fusion: -0.4 us
//   R18 TILES=2 (2 generations) regresses: keep TILES=4, 2048 blocks
// ---------------------------------------------------------------------------

typedef float f32x4 __attribute__((ext_vector_type(4)));

#if defined(__has_builtin)
#if __has_builtin(__builtin_amdgcn_sqrtf)
#define FSQRT(x) __builtin_amdgcn_sqrtf(x)
#endif
#endif
#ifndef FSQRT
#define FSQRT(x) sqrtf(x)
#endif

__device__ __forceinline__ float rfl(float v) {
    return __int_as_float(__builtin_amdgcn_readfirstlane(__float_as_int(v)));
}
__device__ __forceinline__ int rfl(int v) {
    return __builtin_amdgcn_readfirstlane(v);
}

#define TILES 4   // 4 x 256 samples per block; 2M / 1024 = 2048 blocks exact

__global__ __launch_bounds__(256, 8) void vqc_main(const f32x4* __restrict__ x,
                                                   const float* __restrict__ theta,
                                                   float* __restrict__ out,
                                                   int nsamp) {
    // wave-private double-buffered staging: [wave][buf][640 floats]
    __shared__ float sBuf[4][2][640];   // 20 KB

    int tid = threadIdx.x;
    int wid = tid >> 6;
    int lane = tid & 63;

    long long base = (long long)blockIdx.x * (TILES * 256);

    // FRONT-LOAD all 4 tiles of x (issued back-to-back; 4 outstanding vmem).
    f32x4 xv[TILES];
#pragma unroll
    for (int t = 0; t < TILES; ++t) {
        long long bt = base + (long long)t * 256 + tid;
        if (bt < nsamp) xv[t] = x[bt];
    }

    // Uniform monomial coefficients (SGPR), stages 0..3 = RY1, 4..7 = RY2.
    float w[8];
    int   ct[8];          // 1 = cot form (|s| > |c|), 0 = tan form
    float scale = 1.0f;
#pragma unroll
    for (int q = 0; q < 8; ++q) {
        float h = 0.5f * theta[q];
        float c = __cosf(h), s = __sinf(h);
        int cot = rfl(fabsf(s) > fabsf(c) ? 1 : 0);
        ct[q] = cot;
        w[q]  = rfl(cot ? (c / s) : (s / c));
        scale *= cot ? s : c;
    }
    scale = rfl(scale);

#pragma unroll
    for (int t = 0; t < TILES; ++t) {
        long long tileStart = base + (long long)t * 256;
        long long b = tileStart + tid;

        int p = t & 1;
        float* myBuf = sBuf[wid][p];

        if (b < nsamp) {
            // ---- per-qubit 2-vectors (amp bit q) ----
            float va[4], vb[4];
            if (b == 0) {
                // little-endian, raw probs, no sqrt: amp bit q <-> x qubit q
                va[0] = 1.0f - xv[t].x; vb[0] = xv[t].x;
                va[1] = 1.0f - xv[t].y; vb[1] = xv[t].y;
                va[2] = 1.0f - xv[t].z; vb[2] = xv[t].z;
                va[3] = 1.0f - xv[t].w; vb[3] = xv[t].w;
            } else {
                // big-endian, squared probs, sqrt: amp bit q <-> x qubit 3-q
                float p0 = xv[t].x * xv[t].x, p1 = xv[t].y * xv[t].y;
                float p2 = xv[t].z * xv[t].z, p3 = xv[t].w * xv[t].w;
                va[0] = FSQRT(1.0f - p3); vb[0] = FSQRT(p3);
                va[1] = FSQRT(1.0f - p2); vb[1] = FSQRT(p2);
                va[2] = FSQRT(1.0f - p1); vb[2] = FSQRT(p1);
                va[3] = FSQRT(1.0f - p0); vb[3] = FSQRT(p0);
            }

            // ---- RY1 fused: rotate each 2-vector (monomial, 2 FMA each) ----
#pragma unroll
            for (int q = 0; q < 4; ++q) {
                float A = va[q], B = vb[q];
                if (ct[q]) { va[q] = fmaf(w[q], A, -B); vb[q] = fmaf(w[q], B, A); }
                else       { va[q] = fmaf(-w[q], B, A); vb[q] = fmaf(w[q], A, B); }
            }

            // fold total uniform scale into qubit-3 vector
            va[3] *= scale; vb[3] *= scale;

            // ---- outer-product amp build ----
            float hi[4] = { va[3] * va[2], va[3] * vb[2],
                            vb[3] * va[2], vb[3] * vb[2] };
            float lo[4] = { va[1] * va[0], va[1] * vb[0],
                            vb[1] * va[0], vb[1] * vb[0] };
            float amp[16];
#pragma unroll
            for (int k = 0; k < 16; ++k)
                amp[k] = hi[k >> 2] * lo[k & 3];

            // D: sign flips at k = 3, 6, 9, 12
            amp[3]  = -amp[3];
            amp[6]  = -amp[6];
            amp[9]  = -amp[9];
            amp[12] = -amp[12];

            // ---- RY2 monomial butterflies (bits 0..2) ----
#define BFLY(Q, W, CT)                                                   \
            if (CT) {                                                    \
                _Pragma("unroll")                                        \
                for (int i0 = 0; i0 < 16; ++i0)                          \
                    if (!(i0 & (1 << (Q)))) {                            \
                        int i1 = i0 | (1 << (Q));                        \
                        float A = amp[i0], B = amp[i1];                  \
                        amp[i0] = fmaf((W), A, -B);                      \
                        amp[i1] = fmaf((W), B, A);                       \
                    }                                                    \
            } else {                                                     \
                _Pragma("unroll")                                        \
                for (int i0 = 0; i0 < 16; ++i0)                          \
                    if (!(i0 & (1 << (Q)))) {                            \
                        int i1 = i0 | (1 << (Q));                        \
                        float A = amp[i0], B = amp[i1];                  \
                        amp[i0] = fmaf(-(W), B, A);                      \
                        amp[i1] = fmaf((W), A, B);                       \
                    }                                                    \
            }

            BFLY(0, w[4], ct[4])
            BFLY(1, w[5], ct[5])
            BFLY(2, w[6], ct[6])
#undef BFLY

            // RY2 qubit-3 stage: only the 10 needed rows
            float r[10];
            if (ct[7]) {
#pragma unroll
                for (int i = 0; i < 8; ++i)
                    r[i] = fmaf(w[7], amp[i], -amp[i + 8]);
                r[8] = fmaf(w[7], amp[8], amp[0]);
                r[9] = fmaf(w[7], amp[9], amp[1]);
            } else {
#pragma unroll
                for (int i = 0; i < 8; ++i)
                    r[i] = fmaf(-w[7], amp[i + 8], amp[i]);
                r[8] = fmaf(w[7], amp[0], amp[8]);
                r[9] = fmaf(w[7], amp[1], amp[9]);
            }

#pragma unroll
            for (int c = 0; c < 10; ++c)
                myBuf[lane * 10 + c] = r[c] * r[c];   // 4-way bank alias: ~free
        }

        // drain OWN ds ops - intra-wave only, no barrier (wave-private slice)
        asm volatile("s_waitcnt lgkmcnt(0)" ::: "memory");

        long long waveBase = tileStart + (long long)(wid << 6);
        long long wrem = (long long)nsamp - waveBase;
        if (wrem >= 64) {
            // wave's 64 samples = 2560B contiguous in out, line-aligned.
            // NONTEMPORAL: out is write-once -> no-allocate, no L2/L3 churn.
            f32x4* ov = (f32x4*)(out + waveBase * 10);
            const f32x4* sv = (const f32x4*)myBuf;
#pragma unroll
            for (int i = lane; i < 160; i += 64)
                __builtin_nontemporal_store(sv[i], &ov[i]);
        } else if (wrem > 0) {
            int n = (int)wrem * 10;
            for (int i = lane; i < n; i += 64)
                out[waveBase * 10 + i] = myBuf[i];
        }
        // WAR on buffer p (reused at t+2): protected by the lgkmcnt(0) at
        // t+1, which drains this tile's flush ds_reads before t+2's writes.
    }
}

extern "C" void kernel_launch(void* const* d_in, const int* in_sizes, int n_in,
                              void* d_out, int out_size, void* d_ws, size_t ws_size,
                              hipStream_t stream) {
    const float* x = (const float*)d_in[0];      // [B,4] f32
    const float* theta = (const float*)d_in[1];  // [8]   f32
    float* out = (float*)d_out;                  // [B,10] f32

    int nsamp = in_sizes[0] / 4;
    int spb = TILES * 256;
    int blocks = (nsamp + spb - 1) / spb;
    vqc_main<<<blocks, 256, 0, stream>>>((const f32x4*)x, theta, out, nsamp);
}